// Round 7
// baseline (232.486 us; speedup 1.0000x reference)
//
#include <hip/hip_runtime.h>
#include <math.h>

// Causal depthwise conv1d K=4 + SiLU. x (B=4, T=4096, C=2048) fp32, kernel (4, C) fp32.
// y[b,t,c] = silu( sum_j k[j,c] * x[b,t-j,c] ), zero-padded; next_cache = x[:, T-3:, :].
//
// R8 post-mortem: CRASH was an OOB halo read. TG=2 -> first nonzero t-group t0=2
//   reaches x[t0-3] = x[-1]; for b=0 that's before the buffer -> page fault/SIGABRT.
//   All earlier shapes had TG>=4 so (t0!=0 => t0-3>=1) held implicitly. Also a
//   correctness bug: rows 2,3 need x[-1]=0, not memory garbage.
// R9: same TLP experiment (the only lever that ever moved this kernel:
//   1024 blk=82us, 4096=82, 8192=73), boundary fixed: block-uniform partial-zero
//   halo for t0<3 (only 2 of 2048 t-groups). 16384 blocks x 256 thr, TG=2,
//   9 loads + 2 stores/thread, launch_bounds(256,8) -> <=64 VGPR, 8 waves/SIMD.

#define B_   4
#define T_   4096
#define C_   2048
#define K_   4
#define C4_  (C_ / 4)   // 512 float4 groups per row
#define TG_  2          // t rows per thread
#define NT_  (T_ / TG_) // 2048 t-groups

typedef float f4 __attribute__((ext_vector_type(4)));

__device__ __forceinline__ float silu_f(float v) {
    return v * __builtin_amdgcn_rcpf(1.f + __expf(-v));
}

__global__ __launch_bounds__(256, 8) void dwconv_silu_kernel(
    const f4* __restrict__ x,      // [B, T, C4]
    const f4* __restrict__ kern,   // [K, C4]
    f4* __restrict__ y,            // [B, T, C4]
    f4* __restrict__ cache)        // [B, K-1, C4]
{
    // Linear thread id over (b, tg, c4): lanes span consecutive c4 -> every
    // load/store is a contiguous 1 KB wave transaction.
    const int j  = blockIdx.x * 256 + threadIdx.x;
    const int c4 = j & (C4_ - 1);
    const int tg = (j >> 9) & (NT_ - 1);
    const int b  = j >> 20;            // 9 bits c4 + 11 bits tg
    const int t0 = tg * TG_;

    const f4* xp = x + (((size_t)b * T_ + t0) * C4_ + c4);

    // kern first: L1/L2-hot, oldest in the vmcnt queue.
    const f4 k0 = kern[0 * C4_ + c4];
    const f4 k1 = kern[1 * C4_ + c4];
    const f4 k2 = kern[2 * C4_ + c4];
    const f4 k3 = kern[3 * C4_ + c4];

    // Halo rows x[t0-3..t0-1] with zero-padding below t=0. t0 is block-uniform,
    // so these branches never diverge; only t0 in {0,2} takes the partial path.
    f4 m3, m2, m1;
    if (t0 >= 3) {
        m3 = xp[-3 * C4_];
        m2 = xp[-2 * C4_];
        m1 = xp[-1 * C4_];
    } else {
        const f4 z = (f4){0.f, 0.f, 0.f, 0.f};
        m3 = z;                                   // t0-3 < 0 always here
        m2 = (t0 >= 2) ? xp[-2 * C4_] : z;        // t0==2: x[0]
        m1 = (t0 >= 1) ? xp[-1 * C4_] : z;        // t0==2: x[1]
    }
    // Body rows x[t0], x[t0+1].
    const f4 a0 = xp[0 * C4_];
    const f4 a1 = xp[1 * C4_];

#define CONV1(r, a, w1, w2, w3)                                              \
    r.x = fmaf(k0.x, a.x, fmaf(k1.x, w1.x, fmaf(k2.x, w2.x, k3.x * w3.x)));  \
    r.y = fmaf(k0.y, a.y, fmaf(k1.y, w1.y, fmaf(k2.y, w2.y, k3.y * w3.y)));  \
    r.z = fmaf(k0.z, a.z, fmaf(k1.z, w1.z, fmaf(k2.z, w2.z, k3.z * w3.z)));  \
    r.w = fmaf(k0.w, a.w, fmaf(k1.w, w1.w, fmaf(k2.w, w2.w, k3.w * w3.w)));  \
    r.x = silu_f(r.x); r.y = silu_f(r.y); r.z = silu_f(r.z); r.w = silu_f(r.w);

    f4 r0, r1;
    CONV1(r0, a0, m1, m2, m3)
    CONV1(r1, a1, a0, m1, m2)
#undef CONV1

    f4* yp = y + (((size_t)b * T_ + t0) * C4_ + c4);
    yp[0 * C4_] = r0;
    yp[1 * C4_] = r1;

    // Fused next_cache = x[:, T-3:, :]: the last t-group (t0 = T-2) holds
    // m1 = x[T-3], a0 = x[T-2], a1 = x[T-1].
    if (tg == NT_ - 1) {
        f4* cb = cache + (size_t)b * (K_ - 1) * C4_ + c4;
        cb[0 * C4_] = m1;
        cb[1 * C4_] = a0;
        cb[2 * C4_] = a1;
    }
}

extern "C" void kernel_launch(void* const* d_in, const int* in_sizes, int n_in,
                              void* d_out, int out_size, void* d_ws, size_t ws_size,
                              hipStream_t stream)
{
    const f4* x    = (const f4*)d_in[0];
    const f4* kern = (const f4*)d_in[1];
    float*    out  = (float*)d_out;

    f4* y     = (f4*)out;
    f4* cache = (f4*)(out + (size_t)B_ * T_ * C_);

    const int total_threads = B_ * NT_ * C4_;          // 4,194,304
    dim3 grid(total_threads / 256);                    // 16384 blocks
    dim3 block(256);
    dwconv_silu_kernel<<<grid, block, 0, stream>>>(x, kern, y, cache);
}